// Round 6
// baseline (221.272 us; speedup 1.0000x reference)
//
#include <hip/hip_runtime.h>
#include <hip/hip_bf16.h>

#define B_ 8
#define N_ 4096
#define C_ 512
#define H_ 4
#define EPS_ 1e-4f
#define E60P 1.14200739e26f   // expf(60)
#define E60M 8.7565108e-27f   // expf(-60)

typedef __attribute__((ext_vector_type(8))) short short8;
typedef __attribute__((ext_vector_type(4))) float floatx4;
typedef __attribute__((ext_vector_type(2))) float floatx2;
typedef __attribute__((ext_vector_type(4))) unsigned short ushort4_t;
typedef unsigned short ushort_t;

__device__ __forceinline__ float sigmoidf_(float v) {
    return 1.0f / (1.0f + expf(-v));
}

// Fragment-packed layout for GEMM operands (Z and W):
//   chunk(tile t, half w, k0, ks, f) = 512 bf16 (1 KiB) in exact MFMA lane
//   order: element lane*8+kb holds Op[t*128+w*64+f*16+(lane&15)]
//                                   [k0*64+ks*32+(lane>>4)*8+kb]
__device__ __forceinline__ int pk_off(int t, int w, int k0, int ks, int f,
                                      int lane8, int kb) {
    return ((((t * 2 + w) * 16 + k0) * 2 + ks) * 4 + f) * 512 + lane8 * 8 + kb;
}

// async global->LDS, 16 B per lane (dest must be linear: base + lane*16)
__device__ __forceinline__ void gload16(const void* g, void* l) {
    __builtin_amdgcn_global_load_lds(
        (const __attribute__((address_space(1))) void*)g,
        (__attribute__((address_space(3))) void*)l, 16, 0, 0);
}

// ---------------------------------------------------------------------------
// K1: per-subchunk partial sums, ONE direction per block; cvtw folded in
// as blocks 2048..2559. grid 2560; launch_bounds(256,8) -> 8 waves/SIMD.
// ---------------------------------------------------------------------------
__global__ __launch_bounds__(256, 8) void k_partials6(
    const float* __restrict__ x, const float* __restrict__ al,
    const float* __restrict__ dl, const float* __restrict__ bl,
    float* __restrict__ P,
    const float* __restrict__ pw, ushort_t* __restrict__ Wp)
{
    int bid   = blockIdx.x;

    // ---- folded cvtw: proj_w fp32 -> fragment-packed bf16 (512 blocks)
    if (bid >= 2048) {
        int i4 = (bid - 2048) * 256 + threadIdx.x;   // 131072 total
        int i  = i4 << 2;
        int n = i >> 10, k = i & 1023;
        int nt = n >> 7, rn = n & 127;
        int k0 = k >> 6, kk = k & 63;
        int off = pk_off(nt, rn >> 6, k0, kk >> 5, (rn >> 4) & 3,
                         ((kk >> 3) & 3) * 16 + (rn & 15), kk & 7);
        float4 v = ((const float4*)pw)[i4];
        ushort4_t r;
        { __hip_bfloat16 t = __float2bfloat16(v.x); r.x = *(ushort_t*)&t; }
        { __hip_bfloat16 t = __float2bfloat16(v.y); r.y = *(ushort_t*)&t; }
        { __hip_bfloat16 t = __float2bfloat16(v.z); r.z = *(ushort_t*)&t; }
        { __hip_bfloat16 t = __float2bfloat16(v.w); r.w = *(ushort_t*)&t; }
        *(ushort4_t*)&Wp[off] = r;
        return;
    }

    int chunk = bid & 15;
    int ct    = (bid >> 4) & 7;
    int b     = (bid >> 7) & 7;
    int dir   = bid >> 10;
    int lane  = threadIdx.x & 63;
    int wave  = threadIdx.x >> 6;
    int c     = ct * 64 + lane;
    int sub   = chunk * 4 + wave;     // fwd subchunk 0..63
    int t0f   = sub * 64;
    int t0b   = (63 - sub) * 64;      // bwd subchunk start (reversed time)

    float aa[4], dd[4], bb[4];
    { float4 v = ((const float4*)al)[c]; aa[0]=v.x; aa[1]=v.y; aa[2]=v.z; aa[3]=v.w; }
    { float4 v = ((const float4*)dl)[c]; dd[0]=v.x; dd[1]=v.y; dd[2]=v.z; dd[3]=v.w; }
    { float4 v = ((const float4*)bl)[c]; bb[0]=v.x; bb[1]=v.y; bb[2]=v.z; bb[3]=v.w; }

    float A[H_], ri[H_], Lh[H_];
    #pragma unroll
    for (int h = 0; h < H_; ++h) {
        float alpha = sigmoidf_(aa[h]);
        float delta = sigmoidf_(dd[h]);
        float beta  = sigmoidf_(bb[h]);
        A[h] = alpha * beta;
        float r = fminf(fmaxf(1.0f - alpha * delta, EPS_), 1.0f - EPS_);
        Lh[h] = logf(r);
        ri[h] = 1.0f / r;
    }
    floatx2 ri2[2]  = {{ri[0], ri[1]}, {ri[2], ri[3]}};
    floatx2 AEP2[2] = {{A[0] * E60P, A[1] * E60P}, {A[2] * E60P, A[3] * E60P}};

    const float* xp = x + ((size_t)b * N_ + t0f) * C_ + c;

    int   t0   = dir ? t0b : t0f;
    floatx2 Ae2[2], T2[2];
    #pragma unroll
    for (int p = 0; p < 2; ++p) {
        Ae2[p] = (floatx2){A[2*p]   * expf(fminf(-Lh[2*p]   * (float)t0, 60.0f)),
                           A[2*p+1] * expf(fminf(-Lh[2*p+1] * (float)t0, 60.0f))};
        T2[p]  = (floatx2){0.f, 0.f};
    }

    if (dir == 0) {
        float cur[8];
        #pragma unroll
        for (int j = 0; j < 8; ++j) cur[j] = xp[(size_t)j * C_];
        #pragma unroll 1
        for (int g = 0; g < 8; ++g) {
            float nxt[8];
            if (g < 7) {
                #pragma unroll
                for (int j = 0; j < 8; ++j)
                    nxt[j] = xp[(size_t)(g * 8 + 8 + j) * C_];
            }
            #pragma unroll
            for (int j = 0; j < 8; ++j) {
                floatx2 xv2 = {cur[j], cur[j]};
                #pragma unroll
                for (int p = 0; p < 2; ++p) {
                    T2[p] += Ae2[p] * xv2;
                    Ae2[p] = __builtin_elementwise_min(Ae2[p] * ri2[p], AEP2[p]);
                }
            }
            if (g < 7) {
                #pragma unroll
                for (int j = 0; j < 8; ++j) cur[j] = nxt[j];
            }
        }
        float* pp = P + ((size_t)b * 64 + sub) * (H_ * C_) + c;
        pp[0]      = T2[0].x;  pp[C_]     = T2[0].y;
        pp[2 * C_] = T2[1].x;  pp[3 * C_] = T2[1].y;
    } else {
        float cur[8];
        #pragma unroll
        for (int j = 0; j < 8; ++j) cur[j] = xp[(size_t)(63 - j) * C_];
        #pragma unroll 1
        for (int g = 0; g < 8; ++g) {
            float nxt[8];
            if (g < 7) {
                #pragma unroll
                for (int j = 0; j < 8; ++j)
                    nxt[j] = xp[(size_t)(63 - (g * 8 + 8 + j)) * C_];
            }
            #pragma unroll
            for (int j = 0; j < 8; ++j) {
                floatx2 xv2 = {cur[j], cur[j]};
                #pragma unroll
                for (int p = 0; p < 2; ++p) {
                    T2[p] += Ae2[p] * xv2;
                    Ae2[p] = __builtin_elementwise_min(Ae2[p] * ri2[p], AEP2[p]);
                }
            }
            if (g < 7) {
                #pragma unroll
                for (int j = 0; j < 8; ++j) cur[j] = nxt[j];
            }
        }
        float* pp = P + ((size_t)(8 + b) * 64 + (63 - sub)) * (H_ * C_) + c;
        pp[0]      = T2[0].x;  pp[C_]     = T2[0].y;
        pp[2 * C_] = T2[1].x;  pp[3 * C_] = T2[1].y;
    }
}

// ---------------------------------------------------------------------------
// K2: exclusive scan over the 64 subchunks, per (dir,b,c,h).
// Register-resident: 64 independent loads in flight.
// ---------------------------------------------------------------------------
__global__ __launch_bounds__(256) void k_scan(float* __restrict__ P)
{
    int bid = blockIdx.x;
    int ct  = bid & 7;
    int b   = (bid >> 3) & 7;
    int dir = bid >> 6;
    int cl  = threadIdx.x & 63;
    int h   = threadIdx.x >> 6;
    int c   = ct * 64 + cl;

    float* base = P + ((size_t)(dir * 8 + b) * 64) * (H_ * C_) + h * C_ + c;

    float v[64];
    #pragma unroll
    for (int s = 0; s < 64; ++s) v[s] = base[s * (H_ * C_)];

    float run = 0.0f;
    #pragma unroll
    for (int s = 0; s < 64; ++s) { float t = v[s]; v[s] = run; run += t; }

    #pragma unroll
    for (int s = 0; s < 64; ++s) base[s * (H_ * C_)] = v[s];
}

// ---------------------------------------------------------------------------
// K3: apply, ONE direction per block, LDS-staged output tile (r5 version:
// 2 B ds_write per step, coalesced 8x16 B global flush per lane).
// ---------------------------------------------------------------------------
__global__ __launch_bounds__(256, 5) void k_apply6(
    const float* __restrict__ x, const float* __restrict__ al,
    const float* __restrict__ dl, const float* __restrict__ bl,
    const float* __restrict__ eta, const float* __restrict__ P,
    ushort_t* __restrict__ Zp)
{
    __shared__ __align__(16) ushort_t zlds[4][4096];   // 8 KB per wave

    int bid   = blockIdx.x;
    int chunk = bid & 15;
    int ct    = (bid >> 4) & 7;
    int b     = (bid >> 7) & 7;
    int dir   = bid >> 10;
    int lane  = threadIdx.x & 63;
    int wave  = threadIdx.x >> 6;
    int c     = ct * 64 + lane;
    int sub   = chunk * 4 + wave;
    int t0f   = sub * 64;
    int t0b   = (63 - sub) * 64;

    int mt  = b * 32 + (t0f >> 7);
    int wq  = (t0f >> 6) & 1;
    char* zw = (char*)&zlds[wave][0];

    float aa[4], dd[4], bb[4], ee[4];
    { float4 v = ((const float4*)al )[c]; aa[0]=v.x; aa[1]=v.y; aa[2]=v.z; aa[3]=v.w; }
    { float4 v = ((const float4*)dl )[c]; dd[0]=v.x; dd[1]=v.y; dd[2]=v.z; dd[3]=v.w; }
    { float4 v = ((const float4*)bl )[c]; bb[0]=v.x; bb[1]=v.y; bb[2]=v.z; bb[3]=v.w; }
    { float4 v = ((const float4*)eta)[c]; ee[0]=v.x; ee[1]=v.y; ee[2]=v.z; ee[3]=v.w; }

    float A[H_], rr[H_], ri[H_], Lh[H_];
    #pragma unroll
    for (int h = 0; h < H_; ++h) {
        float alpha = sigmoidf_(aa[h]);
        float delta = sigmoidf_(dd[h]);
        float beta  = sigmoidf_(bb[h]);
        A[h] = alpha * beta;
        float r = fminf(fmaxf(1.0f - alpha * delta, EPS_), 1.0f - EPS_);
        Lh[h] = logf(r);
        rr[h] = r;
        ri[h] = 1.0f / r;
    }
    const floatx2 E2M = {E60M, E60M};
    floatx2 ri2[2]  = {{ri[0], ri[1]}, {ri[2], ri[3]}};
    floatx2 rr2[2]  = {{rr[0], rr[1]}, {rr[2], rr[3]}};
    floatx2 ee2[2]  = {{ee[0], ee[1]}, {ee[2], ee[3]}};
    floatx2 AEP2[2] = {{A[0] * E60P, A[1] * E60P}, {A[2] * E60P, A[3] * E60P}};

    const float* xp = x + ((size_t)b * N_ + t0f) * C_ + c;

    if (dir == 0) {
        const float* cp = P + ((size_t)b * 64 + sub) * (H_ * C_) + c;
        floatx2 Ae2[2], em2[2], S2[2];
        #pragma unroll
        for (int p = 0; p < 2; ++p) {
            Ae2[p] = (floatx2){A[2*p]   * expf(fminf(-Lh[2*p]   * (float)t0f, 60.0f)),
                               A[2*p+1] * expf(fminf(-Lh[2*p+1] * (float)t0f, 60.0f))};
            em2[p] = (floatx2){expf(fmaxf( Lh[2*p]   * (float)t0f, -60.0f)),
                               expf(fmaxf( Lh[2*p+1] * (float)t0f, -60.0f))};
            S2[p]  = (floatx2){cp[(2*p) * C_], cp[(2*p+1) * C_]};
        }
        float cur[8];
        #pragma unroll
        for (int j = 0; j < 8; ++j) cur[j] = xp[(size_t)j * C_];
        #pragma unroll 1
        for (int g = 0; g < 8; ++g) {
            float nxt[8];
            if (g < 7) {
                #pragma unroll
                for (int j = 0; j < 8; ++j)
                    nxt[j] = xp[(size_t)(g * 8 + 8 + j) * C_];
            }
            #pragma unroll
            for (int j = 0; j < 8; ++j) {
                int i = g * 8 + j;
                floatx2 xv2 = {cur[j], cur[j]};
                floatx2 acc = {0.f, 0.f};
                #pragma unroll
                for (int p = 0; p < 2; ++p) {
                    S2[p] += Ae2[p] * xv2;
                    Ae2[p] = __builtin_elementwise_min(Ae2[p] * ri2[p], AEP2[p]);
                    acc   += ee2[p] * (em2[p] * S2[p]);
                    em2[p] = __builtin_elementwise_max(em2[p] * rr2[p], E2M);
                }
                float y = acc.x + acc.y;
                __hip_bfloat16 yb = __float2bfloat16(y);
                int bo = (i * 128 + lane * 2) ^ ((i & 7) << 4);
                *(ushort_t*)(zw + bo) = *(ushort_t*)&yb;
            }
            if (g < 7) {
                #pragma unroll
                for (int j = 0; j < 8; ++j) cur[j] = nxt[j];
            }
        }
    } else {
        const float* cp = P + ((size_t)(8 + b) * 64 + (63 - sub)) * (H_ * C_) + c;
        floatx2 Ae2[2], em2[2], S2[2];
        #pragma unroll
        for (int p = 0; p < 2; ++p) {
            Ae2[p] = (floatx2){A[2*p]   * expf(fminf(-Lh[2*p]   * (float)t0b, 60.0f)),
                               A[2*p+1] * expf(fminf(-Lh[2*p+1] * (float)t0b, 60.0f))};
            em2[p] = (floatx2){expf(fmaxf( Lh[2*p]   * (float)t0b, -60.0f)),
                               expf(fmaxf( Lh[2*p+1] * (float)t0b, -60.0f))};
            S2[p]  = (floatx2){cp[(2*p) * C_], cp[(2*p+1) * C_]};
        }
        float cur[8];
        #pragma unroll
        for (int j = 0; j < 8; ++j) cur[j] = xp[(size_t)(63 - j) * C_];
        #pragma unroll 1
        for (int g = 0; g < 8; ++g) {
            float nxt[8];
            if (g < 7) {
                #pragma unroll
                for (int j = 0; j < 8; ++j)
                    nxt[j] = xp[(size_t)(63 - (g * 8 + 8 + j)) * C_];
            }
            #pragma unroll
            for (int j = 0; j < 8; ++j) {
                int i = 63 - (g * 8 + j);
                floatx2 xv2 = {cur[j], cur[j]};
                floatx2 acc = {0.f, 0.f};
                #pragma unroll
                for (int p = 0; p < 2; ++p) {
                    S2[p] += Ae2[p] * xv2;
                    Ae2[p] = __builtin_elementwise_min(Ae2[p] * ri2[p], AEP2[p]);
                    acc   += ee2[p] * (em2[p] * S2[p]);
                    em2[p] = __builtin_elementwise_max(em2[p] * rr2[p], E2M);
                }
                float y = acc.x + acc.y;
                __hip_bfloat16 yb = __float2bfloat16(y);
                int bo = (i * 128 + lane * 2) ^ ((i & 7) << 4);
                *(ushort_t*)(zw + bo) = *(ushort_t*)&yb;
            }
            if (g < 7) {
                #pragma unroll
                for (int j = 0; j < 8; ++j) cur[j] = nxt[j];
            }
        }
    }

    __syncthreads();

    // ---- coalesced flush: wave's 8 KB chunk, 8 x 16 B per lane
    {
        int k0c = dir ? (8 + ct) : ct;
        size_t cb = ((size_t)((mt * 2 + wq) * 16 + k0c)) * 4096;   // elements
        #pragma unroll
        for (int ks = 0; ks < 2; ++ks)
            #pragma unroll
            for (int f = 0; f < 4; ++f) {
                int row = f * 16 + (lane & 15);
                int rb  = (row * 128 + ks * 64 + (lane >> 4) * 16) ^ ((row & 7) << 4);
                short8 v = *(const short8*)(zw + rb);
                *(short8*)(Zp + cb + (ks * 4 + f) * 512 + lane * 8) = v;
            }
    }
}

// ---------------------------------------------------------------------------
// K4: GEMM out[32768,512] = Z @ W^T + bias, operands fragment-packed.
// Double-buffered pipeline (T3-minimum): STAGE(buf^1, k+1) issued BEFORE
// ds_read+MFMA of buf[cur]; single vmcnt(0)+barrier per K-step at the END,
// so the 32-MFMA cluster + 16 ds_reads hide the staging latency.
// LDS 64 KB -> 2 blocks/CU. XCD swizzle: bid&7 = XCD = mt&7.
// ---------------------------------------------------------------------------
__global__ __launch_bounds__(256, 2) void k_gemm5(
    const ushort_t* __restrict__ Zp, const ushort_t* __restrict__ Wp,
    const float* __restrict__ bias, float* __restrict__ out)
{
    __shared__ __align__(16) char lds[65536];   // [2][A 16K | B 16K]
    float* stg = (float*)lds;                    // epilogue reuse (16896 B)

    int tid  = threadIdx.x;
    int lane = tid & 63, wave = tid >> 6;
    int wm   = wave & 1, wn = wave >> 1;
    int fr   = lane & 15, quad = lane >> 4;

    int bid = blockIdx.x;
    int mt  = ((bid >> 5) << 3) | (bid & 7);   // mt & 7 == bid & 7 == XCD
    int nt  = (bid >> 3) & 3;
    int m0  = mt * 128, n0 = nt * 128;

    const ushort_t* Az = Zp + ((size_t)(mt * 2) * 16) * 4096;  // w-half stride 65536
    const ushort_t* Bz = Wp + ((size_t)(nt * 2) * 16) * 4096;

    floatx4 acc[4][4];
    #pragma unroll
    for (int mf = 0; mf < 4; ++mf)
        #pragma unroll
        for (int nf = 0; nf < 4; ++nf)
            acc[mf][nf] = (floatx4){0.f, 0.f, 0.f, 0.f};

    // stage K-step k0 into buffer bi (32 KB: A 16K + B 16K)
    auto STAGE = [&](int bi, int k0) {
        char* ldsA = lds + bi * 32768;
        char* ldsB = ldsA + 16384;
        const ushort_t* As = Az + (size_t)k0 * 4096;
        const ushort_t* Bs = Bz + (size_t)k0 * 4096;
        #pragma unroll
        for (int w = 0; w < 2; ++w)
            #pragma unroll
            for (int inst = 0; inst < 2; ++inst) {
                gload16(As + w * 65536 + inst * 2048 + tid * 8,
                        ldsA + w * 8192 + inst * 4096 + tid * 16);
                gload16(Bs + w * 65536 + inst * 2048 + tid * 8,
                        ldsB + w * 8192 + inst * 4096 + tid * 16);
            }
    };

    // prologue: stage k0=0, drain, barrier
    STAGE(0, 0);
    asm volatile("s_waitcnt vmcnt(0)" ::: "memory");
    __syncthreads();

    int cur = 0;
    for (int k0 = 0; k0 < 16; ++k0) {
        if (k0 < 15) STAGE(cur ^ 1, k0 + 1);     // prefetch next tile
        __builtin_amdgcn_sched_barrier(0);        // loads issue before reads
        char* ldsA = lds + cur * 32768;
        char* ldsB = ldsA + 16384;
        short8 af[2][4], bf[2][4];
        #pragma unroll
        for (int ks = 0; ks < 2; ++ks)
            #pragma unroll
            for (int f = 0; f < 4; ++f) {
                af[ks][f] = *(const short8*)(ldsA + wm * 8192 + (ks * 4 + f) * 1024 + lane * 16);
                bf[ks][f] = *(const short8*)(ldsB + wn * 8192 + (ks * 4 + f) * 1024 + lane * 16);
            }
        #pragma unroll
        for (int ks = 0; ks < 2; ++ks)
            #pragma unroll
            for (int mf = 0; mf < 4; ++mf)
                #pragma unroll
                for (int nf = 0; nf < 4; ++nf)
                    acc[mf][nf] = __builtin_amdgcn_mfma_f32_16x16x32_bf16(
                        af[ks][mf], bf[ks][nf], acc[mf][nf], 0, 0, 0);
        if (k0 < 15) {
            __builtin_amdgcn_sched_barrier(0);    // MFMAs stay above the wait
            asm volatile("s_waitcnt vmcnt(0)" ::: "memory");
            __syncthreads();
            cur ^= 1;
        }
    }
    __syncthreads();   // all waves done with LDS before epilogue reuse

    // ---- LDS-staged epilogue: 4 chunks of 32 rows, coalesced 512 B rows
    int rrow = tid >> 3;                 // 0..31
    int seg  = tid & 7;                  // 0..7
    int gcol = n0 + seg * 16;

    #pragma unroll
    for (int ch = 0; ch < 4; ++ch) {
        if ((wave & 1) == (ch >> 1)) {
            int ml = (ch & 1) * 2;
            #pragma unroll
            for (int mi = 0; mi < 2; ++mi) {
                #pragma unroll
                for (int nf = 0; nf < 4; ++nf) {
                    int col = wn * 64 + nf * 16 + fr;
                    #pragma unroll
                    for (int rg = 0; rg < 4; ++rg) {
                        int row = mi * 16 + quad * 4 + rg;
                        stg[row * 132 + col] = acc[ml + mi][nf][rg];
                    }
                }
            }
        }
        __syncthreads();
        {
            int gm = m0 + ch * 32 + rrow;
            const float* s = &stg[rrow * 132 + seg * 16];
            #pragma unroll
            for (int k = 0; k < 4; ++k) {
                float4 v  = *(const float4*)&s[k * 4];
                float4 bv = *(const float4*)&bias[gcol + k * 4];
                v.x += bv.x; v.y += bv.y; v.z += bv.z; v.w += bv.w;
                *(float4*)&out[(size_t)gm * 512 + gcol + k * 4] = v;
            }
        }
        __syncthreads();
    }
}

// ---------------------------------------------------------------------------
extern "C" void kernel_launch(void* const* d_in, const int* in_sizes, int n_in,
                              void* d_out, int out_size, void* d_ws, size_t ws_size,
                              hipStream_t stream)
{
    const float* x  = (const float*)d_in[0];
    const float* al = (const float*)d_in[1];
    const float* dl = (const float*)d_in[2];
    const float* bl = (const float*)d_in[3];
    const float* et = (const float*)d_in[4];
    const float* pw = (const float*)d_in[5];
    const float* pb = (const float*)d_in[6];
    float* out = (float*)d_out;

    // workspace:
    //   Zp bf16 packed [32768,1024] : 67,108,864 B
    //   P  f32  [2,B,64,H,C]        :  8,388,608 B
    //   Wp bf16 packed [512,1024]   :  1,048,576 B
    ushort_t* Zp = (ushort_t*)d_ws;
    float*    P  = (float*)((char*)d_ws + 67108864);
    ushort_t* Wp = (ushort_t*)((char*)d_ws + 75497472);

    hipLaunchKernelGGL(k_partials6, dim3(2560), dim3(256), 0, stream,
                       x, al, dl, bl, P, pw, Wp);
    hipLaunchKernelGGL(k_scan,      dim3(128),  dim3(256), 0, stream, P);
    hipLaunchKernelGGL(k_apply6,    dim3(2048), dim3(256), 0, stream,
                       x, al, dl, bl, et, P, Zp);
    hipLaunchKernelGGL(k_gemm5,     dim3(1024), dim3(256), 0, stream,
                       Zp, Wp, pb, out);
}

// Round 7
// 202.826 us; speedup vs baseline: 1.0909x; 1.0909x over previous
//
#include <hip/hip_runtime.h>
#include <hip/hip_bf16.h>

#define B_ 8
#define N_ 4096
#define C_ 512
#define H_ 4
#define EPS_ 1e-4f
#define E60P 1.14200739e26f   // expf(60)
#define E60M 8.7565108e-27f   // expf(-60)

typedef __attribute__((ext_vector_type(8))) short short8;
typedef __attribute__((ext_vector_type(4))) float floatx4;
typedef __attribute__((ext_vector_type(2))) float floatx2;
typedef __attribute__((ext_vector_type(4))) unsigned short ushort4_t;
typedef unsigned short ushort_t;

__device__ __forceinline__ float sigmoidf_(float v) {
    return 1.0f / (1.0f + expf(-v));
}

// Fragment-packed layout for GEMM operands (Z and W):
//   chunk(tile t, half w, k0, ks, f) = 512 bf16 (1 KiB) in exact MFMA lane
//   order: element lane*8+kb holds Op[t*128+w*64+f*16+(lane&15)]
//                                   [k0*64+ks*32+(lane>>4)*8+kb]
__device__ __forceinline__ int pk_off(int t, int w, int k0, int ks, int f,
                                      int lane8, int kb) {
    return ((((t * 2 + w) * 16 + k0) * 2 + ks) * 4 + f) * 512 + lane8 * 8 + kb;
}

// async global->LDS, 16 B per lane (dest must be linear: base + lane*16)
__device__ __forceinline__ void gload16(const void* g, void* l) {
    __builtin_amdgcn_global_load_lds(
        (const __attribute__((address_space(1))) void*)g,
        (__attribute__((address_space(3))) void*)l, 16, 0, 0);
}

// ---------------------------------------------------------------------------
// K_EMA: fused partials + block-local scan + apply. One block handles one
// (dir, b, 32-channel tile) = full N=4096 sequence. 1024 threads =
// (sg 0..31) x (c5 0..31); each thread owns 128 consecutive dir-time steps.
//   phase 1: 128-step clamped-EMA partial -> LDS [sg][c5*4+h]  (16 KB)
//   scan   : 128 threads, serial 32-step exclusive scan per (c5,h)
//   phase 3: apply with prefix; x re-read (L3-resident); packed Zp write
// Eliminates the P array (24 MB HBM round-trips), the scan kernel, and two
// launch gaps. cvtw folded in as blocks 256..383. grid 384 x 1024.
// ---------------------------------------------------------------------------
__global__ __launch_bounds__(1024, 4) void k_ema_fused(
    const float* __restrict__ x, const float* __restrict__ al,
    const float* __restrict__ dl, const float* __restrict__ bl,
    const float* __restrict__ eta, const float* __restrict__ pw,
    ushort_t* __restrict__ Zp, ushort_t* __restrict__ Wp)
{
    int bid = blockIdx.x;
    int tid = threadIdx.x;

    // ---- folded cvtw: proj_w fp32 -> fragment-packed bf16 (128 blocks)
    if (bid >= 256) {
        int i4 = (bid - 256) * 1024 + tid;   // 131072 total
        int i  = i4 << 2;
        int n = i >> 10, k = i & 1023;
        int nt = n >> 7, rn = n & 127;
        int k0 = k >> 6, kk = k & 63;
        int off = pk_off(nt, rn >> 6, k0, kk >> 5, (rn >> 4) & 3,
                         ((kk >> 3) & 3) * 16 + (rn & 15), kk & 7);
        float4 v = ((const float4*)pw)[i4];
        ushort4_t r;
        { __hip_bfloat16 t = __float2bfloat16(v.x); r.x = *(ushort_t*)&t; }
        { __hip_bfloat16 t = __float2bfloat16(v.y); r.y = *(ushort_t*)&t; }
        { __hip_bfloat16 t = __float2bfloat16(v.z); r.z = *(ushort_t*)&t; }
        { __hip_bfloat16 t = __float2bfloat16(v.w); r.w = *(ushort_t*)&t; }
        *(ushort4_t*)&Wp[off] = r;
        return;
    }

    __shared__ float slds[32][128];   // [sg][c5*4+h], 16 KB

    int dir  = bid & 1;
    int b    = (bid >> 1) & 7;
    int ct16 = bid >> 4;              // 0..15 (32-channel tile)
    int c5   = tid & 31;
    int sg   = tid >> 5;              // 0..31
    int c    = ct16 * 32 + c5;

    // ---- weights
    float aa[4], dd[4], bb[4], ee[4];
    { float4 v = ((const float4*)al )[c]; aa[0]=v.x; aa[1]=v.y; aa[2]=v.z; aa[3]=v.w; }
    { float4 v = ((const float4*)dl )[c]; dd[0]=v.x; dd[1]=v.y; dd[2]=v.z; dd[3]=v.w; }
    { float4 v = ((const float4*)bl )[c]; bb[0]=v.x; bb[1]=v.y; bb[2]=v.z; bb[3]=v.w; }
    { float4 v = ((const float4*)eta)[c]; ee[0]=v.x; ee[1]=v.y; ee[2]=v.z; ee[3]=v.w; }

    float A[H_], rr[H_], ri[H_], Lh[H_];
    #pragma unroll
    for (int h = 0; h < H_; ++h) {
        float alpha = sigmoidf_(aa[h]);
        float delta = sigmoidf_(dd[h]);
        float beta  = sigmoidf_(bb[h]);
        A[h] = alpha * beta;
        float r = fminf(fmaxf(1.0f - alpha * delta, EPS_), 1.0f - EPS_);
        Lh[h] = logf(r);
        rr[h] = r;
        ri[h] = 1.0f / r;
    }
    const floatx2 E2M = {E60M, E60M};
    floatx2 ri2[2]  = {{ri[0], ri[1]}, {ri[2], ri[3]}};
    floatx2 rr2[2]  = {{rr[0], rr[1]}, {rr[2], rr[3]}};
    floatx2 ee2[2]  = {{ee[0], ee[1]}, {ee[2], ee[3]}};
    floatx2 AEP2[2] = {{A[0] * E60P, A[1] * E60P}, {A[2] * E60P, A[3] * E60P}};

    int  t0 = sg * 128;                       // dir-relative start time
    int  r0 = dir ? (N_ - 1 - t0) : t0;       // original row at j=0
    long sC = dir ? -(long)C_ : (long)C_;     // row stride (signed)
    const float* xb = x + ((size_t)b * N_ + r0) * C_ + c;

    // ---- phase 1: 128-step partial
    floatx2 Ae2[2], T2[2];
    #pragma unroll
    for (int p = 0; p < 2; ++p) {
        Ae2[p] = (floatx2){A[2*p]   * expf(fminf(-Lh[2*p]   * (float)t0, 60.0f)),
                           A[2*p+1] * expf(fminf(-Lh[2*p+1] * (float)t0, 60.0f))};
        T2[p]  = (floatx2){0.f, 0.f};
    }
    {
        float cur[8];
        #pragma unroll
        for (int j = 0; j < 8; ++j) cur[j] = xb[(long)j * sC];
        #pragma unroll 1
        for (int g = 0; g < 16; ++g) {
            float nxt[8];
            if (g < 15) {
                #pragma unroll
                for (int j = 0; j < 8; ++j)
                    nxt[j] = xb[(long)(g * 8 + 8 + j) * sC];
            }
            #pragma unroll
            for (int j = 0; j < 8; ++j) {
                floatx2 xv2 = {cur[j], cur[j]};
                #pragma unroll
                for (int p = 0; p < 2; ++p) {
                    T2[p] += Ae2[p] * xv2;
                    Ae2[p] = __builtin_elementwise_min(Ae2[p] * ri2[p], AEP2[p]);
                }
            }
            if (g < 15) {
                #pragma unroll
                for (int j = 0; j < 8; ++j) cur[j] = nxt[j];
            }
        }
    }
    *(float4*)&slds[sg][c5 * 4] = (float4){T2[0].x, T2[0].y, T2[1].x, T2[1].y};

    __syncthreads();

    // ---- block-local exclusive scan over sg, per (c5,h); tid 0..127
    if (tid < 128) {
        float run = 0.f;
        #pragma unroll
        for (int s = 0; s < 32; ++s) {
            float v = slds[s][tid];
            slds[s][tid] = run;
            run += v;
        }
    }
    __syncthreads();

    // ---- phase 3: apply with prefix, packed Zp write
    floatx2 em2[2], S2[2];
    {
        float4 pf = *(const float4*)&slds[sg][c5 * 4];
        S2[0] = (floatx2){pf.x, pf.y};
        S2[1] = (floatx2){pf.z, pf.w};
    }
    #pragma unroll
    for (int p = 0; p < 2; ++p) {
        Ae2[p] = (floatx2){A[2*p]   * expf(fminf(-Lh[2*p]   * (float)t0, 60.0f)),
                           A[2*p+1] * expf(fminf(-Lh[2*p+1] * (float)t0, 60.0f))};
        em2[p] = (floatx2){expf(fmaxf( Lh[2*p]   * (float)t0, -60.0f)),
                           expf(fmaxf( Lh[2*p+1] * (float)t0, -60.0f))};
    }

    int cl  = (ct16 & 1) * 32 + c5;           // col within 64-channel group
    int k0c = (dir ? 8 : 0) + (ct16 >> 1);
    int mtv = b * 32 + (dir ? (31 - sg) : sg);
    int ksv = cl >> 5, qv = (cl >> 3) & 3, kbv = cl & 7;
    int offc0 = pk_off(mtv, 0, k0c, ksv, 0, qv * 16, kbv);
    int offc1 = pk_off(mtv, 1, k0c, ksv, 0, qv * 16, kbv);

    {
        float cur[8];
        #pragma unroll
        for (int j = 0; j < 8; ++j) cur[j] = xb[(long)j * sC];
        #pragma unroll 1
        for (int g = 0; g < 16; ++g) {
            float nxt[8];
            if (g < 15) {
                #pragma unroll
                for (int j = 0; j < 8; ++j)
                    nxt[j] = xb[(long)(g * 8 + 8 + j) * sC];
            }
            #pragma unroll
            for (int j = 0; j < 8; ++j) {
                int jj = g * 8 + j;
                floatx2 xv2 = {cur[j], cur[j]};
                floatx2 acc = {0.f, 0.f};
                #pragma unroll
                for (int p = 0; p < 2; ++p) {
                    S2[p] += Ae2[p] * xv2;
                    Ae2[p] = __builtin_elementwise_min(Ae2[p] * ri2[p], AEP2[p]);
                    acc   += ee2[p] * (em2[p] * S2[p]);
                    em2[p] = __builtin_elementwise_max(em2[p] * rr2[p], E2M);
                }
                float y = acc.x + acc.y;
                __hip_bfloat16 yb = __float2bfloat16(y);
                int q6 = (jj >> 6) & 1;
                int wq = dir ? (1 - q6) : q6;
                int ii = dir ? (63 - (jj & 63)) : (jj & 63);
                int off = (wq ? offc1 : offc0) + ((ii >> 4) << 9) + ((ii & 15) << 3);
                Zp[off] = *(ushort_t*)&yb;
            }
            if (g < 15) {
                #pragma unroll
                for (int j = 0; j < 8; ++j) cur[j] = nxt[j];
            }
        }
    }
}

// ---------------------------------------------------------------------------
// K4: GEMM out[32768,512] = Z @ W^T + bias, operands fragment-packed,
// m97 structure (round-1 version: 51 us, best measured; 4 blocks/CU beats
// every pipelining variant tried). XCD swizzle: bid&7 = XCD = mt&7.
// ---------------------------------------------------------------------------
__global__ __launch_bounds__(256, 4) void k_gemm3(
    const ushort_t* __restrict__ Zp, const ushort_t* __restrict__ Wp,
    const float* __restrict__ bias, float* __restrict__ out)
{
    __shared__ __align__(16) char lds[32768];
    char*  ldsA = lds;            // [w][ks*4+f][512 bf16] linear
    char*  ldsB = lds + 16384;
    float* stg  = (float*)lds;

    int tid  = threadIdx.x;
    int lane = tid & 63, wave = tid >> 6;
    int wm   = wave & 1, wn = wave >> 1;
    int fr   = lane & 15, quad = lane >> 4;

    int bid = blockIdx.x;
    int mt  = ((bid >> 5) << 3) | (bid & 7);   // mt & 7 == bid & 7 == XCD
    int nt  = (bid >> 3) & 3;
    int m0  = mt * 128, n0 = nt * 128;

    const ushort_t* Az = Zp + ((size_t)(mt * 2) * 16) * 4096;  // w-half stride 65536
    const ushort_t* Bz = Wp + ((size_t)(nt * 2) * 16) * 4096;

    floatx4 acc[4][4];
    #pragma unroll
    for (int mf = 0; mf < 4; ++mf)
        #pragma unroll
        for (int nf = 0; nf < 4; ++nf)
            acc[mf][nf] = (floatx4){0.f, 0.f, 0.f, 0.f};

    for (int k0 = 0; k0 < 16; ++k0) {
        const ushort_t* As = Az + (size_t)k0 * 4096;
        const ushort_t* Bs = Bz + (size_t)k0 * 4096;
        // stage 32 KB: 8 x global_load_lds_dwordx4 per thread
        #pragma unroll
        for (int w = 0; w < 2; ++w)
            #pragma unroll
            for (int inst = 0; inst < 2; ++inst) {
                gload16(As + w * 65536 + inst * 2048 + tid * 8,
                        ldsA + w * 8192 + inst * 4096 + tid * 16);
                gload16(Bs + w * 65536 + inst * 2048 + tid * 8,
                        ldsB + w * 8192 + inst * 4096 + tid * 16);
            }
        asm volatile("s_waitcnt vmcnt(0)" ::: "memory");
        __syncthreads();

        #pragma unroll
        for (int ks = 0; ks < 2; ++ks) {
            short8 af[4], bf[4];
            #pragma unroll
            for (int f = 0; f < 4; ++f) {
                af[f] = *(const short8*)(ldsA + wm * 8192 + (ks * 4 + f) * 1024 + lane * 16);
                bf[f] = *(const short8*)(ldsB + wn * 8192 + (ks * 4 + f) * 1024 + lane * 16);
            }
            #pragma unroll
            for (int mf = 0; mf < 4; ++mf)
                #pragma unroll
                for (int nf = 0; nf < 4; ++nf)
                    acc[mf][nf] = __builtin_amdgcn_mfma_f32_16x16x32_bf16(
                        af[mf], bf[nf], acc[mf][nf], 0, 0, 0);
        }
        __syncthreads();
    }

    // ---- LDS-staged epilogue: 4 chunks of 32 rows, coalesced 512 B rows
    int rrow = tid >> 3;                 // 0..31
    int seg  = tid & 7;                  // 0..7
    int gcol = n0 + seg * 16;

    #pragma unroll
    for (int ch = 0; ch < 4; ++ch) {
        if ((wave & 1) == (ch >> 1)) {
            int ml = (ch & 1) * 2;
            #pragma unroll
            for (int mi = 0; mi < 2; ++mi) {
                #pragma unroll
                for (int nf = 0; nf < 4; ++nf) {
                    int col = wn * 64 + nf * 16 + fr;
                    #pragma unroll
                    for (int rg = 0; rg < 4; ++rg) {
                        int row = mi * 16 + quad * 4 + rg;
                        stg[row * 132 + col] = acc[ml + mi][nf][rg];
                    }
                }
            }
        }
        __syncthreads();
        {
            int gm = m0 + ch * 32 + rrow;
            const float* s = &stg[rrow * 132 + seg * 16];
            #pragma unroll
            for (int k = 0; k < 4; ++k) {
                float4 v  = *(const float4*)&s[k * 4];
                float4 bv = *(const float4*)&bias[gcol + k * 4];
                v.x += bv.x; v.y += bv.y; v.z += bv.z; v.w += bv.w;
                *(float4*)&out[(size_t)gm * 512 + gcol + k * 4] = v;
            }
        }
        __syncthreads();
    }
}

// ---------------------------------------------------------------------------
extern "C" void kernel_launch(void* const* d_in, const int* in_sizes, int n_in,
                              void* d_out, int out_size, void* d_ws, size_t ws_size,
                              hipStream_t stream)
{
    const float* x  = (const float*)d_in[0];
    const float* al = (const float*)d_in[1];
    const float* dl = (const float*)d_in[2];
    const float* bl = (const float*)d_in[3];
    const float* et = (const float*)d_in[4];
    const float* pw = (const float*)d_in[5];
    const float* pb = (const float*)d_in[6];
    float* out = (float*)d_out;

    // workspace:
    //   Zp bf16 packed [32768,1024] : 67,108,864 B
    //   Wp bf16 packed [512,1024]   :  1,048,576 B
    ushort_t* Zp = (ushort_t*)d_ws;
    ushort_t* Wp = (ushort_t*)((char*)d_ws + 67108864);

    hipLaunchKernelGGL(k_ema_fused, dim3(384),  dim3(1024), 0, stream,
                       x, al, dl, bl, et, pw, Zp, Wp);
    hipLaunchKernelGGL(k_gemm3,     dim3(1024), dim3(256),  0, stream,
                       Zp, Wp, pb, out);
}